// Round 18
// baseline (114.880 us; speedup 1.0000x reference)
//
#include <hip/hip_runtime.h>
#include <math.h>

typedef unsigned short u16;
typedef unsigned int u32;
typedef unsigned long long u64;
typedef __attribute__((ext_vector_type(8))) short short8;
typedef __attribute__((ext_vector_type(4))) short short4v;
typedef __attribute__((ext_vector_type(4))) float f32x4;
typedef __attribute__((ext_vector_type(4))) u16 u16x4;
typedef __attribute__((ext_vector_type(2))) u32 u32x2;
typedef __attribute__((ext_vector_type(4))) u32 u32x4;

#define AS1 __attribute__((address_space(1)))
#define AS3 __attribute__((address_space(3)))

// 0.125 * log2(e): QK^T scores scaled so softmax = exp2
#define QSCALE 0.18033688011112042f

__device__ __forceinline__ u16 f2bf(float f) {
  union { float f; u32 i; } u; u.f = f;
  u32 r = u.i + 0x7FFFu + ((u.i >> 16) & 1u);
  return (u16)(r >> 16);
}

__device__ __forceinline__ u32 pk_bf16(float a, float b) {
  u32 r;
  asm volatile("v_cvt_pk_bf16_f32 %0, %1, %2" : "=v"(r) : "v"(a), "v"(b));
  return r;
}

__device__ __forceinline__ void gl_lds16(const void* g, void* l) {
  __builtin_amdgcn_global_load_lds((const AS1 u32*)g, (AS3 u32*)l, 16, 0, 0);
}

#define MFMA32(a, b, c) __builtin_amdgcn_mfma_f32_16x16x32_bf16(a, b, c, 0, 0, 0)

__device__ __forceinline__ f32x4 mfma16(short4v a, short4v b, f32x4 c) {
#if __has_builtin(__builtin_amdgcn_mfma_f32_16x16x16_bf16)
  return __builtin_amdgcn_mfma_f32_16x16x16_bf16(a, b, c, 0, 0, 0);
#elif __has_builtin(__builtin_amdgcn_mfma_f32_16x16x16bf16_1k)
  return __builtin_amdgcn_mfma_f32_16x16x16bf16_1k(a, b, c, 0, 0, 0);
#else
  f32x4 d = c;
  asm("v_mfma_f32_16x16x16_bf16 %0, %1, %2, %0" : "+v"(d) : "v"(a), "v"(b));
  return d;
#endif
}

// ---------------- fused convert (x + 4 weights) + RoPE table ----------------
__global__ void cvt_all(const float* __restrict__ x,
                        const float* __restrict__ Wq, const float* __restrict__ Wk,
                        const float* __restrict__ Wv, const float* __restrict__ Wp,
                        u16* __restrict__ xb,
                        u16* __restrict__ Wqb, u16* __restrict__ Wkb,
                        u16* __restrict__ Wvb, u16* __restrict__ Wpb,
                        float* __restrict__ cosT, float* __restrict__ sinT,
                        int n4x, int n4tot) {
  int i = blockIdx.x * 256 + threadIdx.x;
  if (i >= n4tot) {                    // RoPE table tail: 65536 items
    int k = i - n4tot;
    int t = k >> 5, j = k & 31;
    float inv = powf(10000.0f, -(float)j / 32.0f);
    float ang = (float)t * inv;
    cosT[k] = cosf(ang);
    sinT[k] = sinf(ang);
    return;
  }
  const float* src; u16* dst; int off;
  if (i < n4x) { src = x; dst = xb; off = i; }
  else {
    int wi = i - n4x;
    int sel = wi >> 18;                // CC/4 = 2^18
    off = wi & ((1 << 18) - 1);
    src = sel == 0 ? Wq : sel == 1 ? Wk : sel == 2 ? Wv : Wp;
    dst = sel == 0 ? Wqb : sel == 1 ? Wkb : sel == 2 ? Wvb : Wpb;
  }
  float4 v = ((const float4*)src)[off];
  u16x4 o = { f2bf(v.x), f2bf(v.y), f2bf(v.z), f2bf(v.w) };
  ((u16x4*)dst)[off] = o;
}

// ---------------- fused QKV GEMM (bf16 MFMA), BK=64, RoPE epilogue ----------------
__global__ __launch_bounds__(256, 3) void gemm_qkv(
    const u16* __restrict__ xb,
    const u16* __restrict__ Wqb, const u16* __restrict__ Wkb, const u16* __restrict__ Wvb,
    const float* __restrict__ bq, const float* __restrict__ bk, const float* __restrict__ bv,
    const float* __restrict__ cosT, const float* __restrict__ sinT,
    u16* __restrict__ Qb, u16* __restrict__ Kb, u16* __restrict__ Vb) {
  const int K = 1024, N = 1024;
  __shared__ __attribute__((aligned(16))) u16 As[128 * 64];
  __shared__ __attribute__((aligned(16))) u16 Bs[128 * 64];
  const int tid = threadIdx.x;
  const int lane = tid & 63;
  const int hi = lane >> 4, cc = lane & 15;
  const int w = tid >> 6, wm = w >> 1, wn = w & 1;

  const int lin = blockIdx.x + 24 * blockIdx.y;   // gridDim (24, 32)
  const int a_ = lin & 7;
  const int m_ = lin >> 3;
  const int c_ = a_ * 3 + (m_ % 3);               // 0..23: sel*8 + colt
  const int sel = c_ >> 3;
  const int row0 = (m_ / 3) * 128, col0 = (c_ & 7) * 128;

  const u16* W = sel == 0 ? Wqb : sel == 1 ? Wkb : Wvb;
  const float* bias = sel == 0 ? bq : sel == 1 ? bk : bv;
  u16* Out = sel == 0 ? Qb : sel == 1 ? Kb : Vb;

  const int lr = tid >> 3;                                   // 0..31
  const int lkb = (((tid & 7) ^ (lr & 7)) * 8);              // pre-swizzled src col
  const u16* Ag = xb + (size_t)(row0 + lr) * K + lkb;
  const u16* Wg = W + (size_t)(col0 + lr) * K + lkb;

  f32x4 acc[4][4];
#pragma unroll
  for (int m = 0; m < 4; ++m)
#pragma unroll
    for (int n = 0; n < 4; ++n) acc[m][n] = f32x4{0.f, 0.f, 0.f, 0.f};

  for (int k0 = 0; k0 < K; k0 += 64) {
    __syncthreads();
#pragma unroll
    for (int j = 0; j < 4; ++j) {
      gl_lds16(Ag + (size_t)j * 32 * K + k0, As + j * 2048 + tid * 8);
      gl_lds16(Wg + (size_t)j * 32 * K + k0, Bs + j * 2048 + tid * 8);
    }
    __syncthreads();
    short8 a[2][4], b[2][4];
#pragma unroll
    for (int kk = 0; kk < 2; ++kk) {
#pragma unroll
      for (int m = 0; m < 4; ++m)
        a[kk][m] = *(const short8*)(As + (wm * 64 + m * 16 + cc) * 64 +
                                    (((kk * 4 + hi) ^ (cc & 7)) * 8));
#pragma unroll
      for (int n = 0; n < 4; ++n)
        b[kk][n] = *(const short8*)(Bs + (wn * 64 + n * 16 + cc) * 64 +
                                    (((kk * 4 + hi) ^ (cc & 7)) * 8));
    }
#pragma unroll
    for (int kk = 0; kk < 2; ++kk)
#pragma unroll
      for (int m = 0; m < 4; ++m)
#pragma unroll
        for (int n = 0; n < 4; ++n)
          acc[m][n] = MFMA32(a[kk][m], b[kk][n], acc[m][n]);
  }

  if (sel < 2) {
    const float qs = (sel == 0) ? QSCALE : 1.0f;
#pragma unroll
    for (int n = 0; n < 4; ++n) {
      const int col = col0 + wn * 64 + n * 16 + cc;
      const int j = (col & 63) >> 1;
      const float bb = bias[col];
#pragma unroll
      for (int m = 0; m < 4; ++m) {
        const int rw = row0 + wm * 64 + m * 16 + hi * 4;
#pragma unroll
        for (int r = 0; r < 4; ++r) {
          const int row = rw + r;
          const int t = row & 2047;
          float v = acc[m][n][r] + bb;
          float pv = __shfl_xor(v, 1);
          float c = cosT[t * 32 + j], s = sinT[t * 32 + j];
          float oo = (cc & 1) ? (s * pv + c * v) : (c * v - s * pv);
          Out[(size_t)row * N + col] = f2bf(oo * qs);
        }
      }
    }
  } else {
#pragma unroll
    for (int n = 0; n < 4; ++n) {
      const int col = col0 + wn * 64 + n * 16 + cc;
      const float bb = bias[col];
#pragma unroll
      for (int m = 0; m < 4; ++m) {
        const int rw = row0 + wm * 64 + m * 16 + hi * 4;
#pragma unroll
        for (int r = 0; r < 4; ++r)
          Out[(size_t)(rw + r) * N + col] = f2bf(acc[m][n][r] + bb);
      }
    }
  }
}

// ---------------- MFMA causal flash attention: 512-thread blocks, reg-P PV (x16) ----------------
// Waves 0-3 own chunk A's 16-row slices; waves 4-7 chunk B's. P never touches
// LDS: the packed softmax output IS the 16x16x16 PV A-fragment (keys hi*4+r
// k-granularity matches). LDS = Ks+Vt = 16 KB.
__global__ __launch_bounds__(512, 3) void flash_mfma(
    const u16* __restrict__ Qb, const u16* __restrict__ Kb,
    const u16* __restrict__ Vb, u16* __restrict__ Yb) {
  const int T = 2048, C = 1024;
  __shared__ __attribute__((aligned(16))) u16 Ks[64 * 64];      // swizzled [key][d]
  __shared__ __attribute__((aligned(16))) u16 Vt[64 * 64];      // swizzled [d][key]

  const int tid = threadIdx.x;
  const int lane = tid & 63;
  const int hi = lane >> 4, cc = lane & 15;
  const int hi4 = hi * 4;
  const int w = tid >> 6;                       // 0..7
  const int wl = w & 3;                         // slice within chunk
  const int isB = w >> 2;                       // 0 = chunk A, 1 = chunk B

  const int lin = blockIdx.x + 16 * blockIdx.y; // gridDim (16, 32)
  const int bh  = (lin & 7) * 4 + ((lin >> 3) & 3);
  const int qtA = lin >> 5;                     // 0..15
  const int qtB = 31 - qtA;                     // 16..31
  const int qtW = isB ? qtB : qtA;              // this wave's chunk
  const size_t hbase = (size_t)(bh >> 4) * T * C + (size_t)(bh & 15) * 64;
  const int q0w = qtW * 64 + wl * 16;

  // Q fragment (B-operand of swapped QK^T; Q pre-scaled by QSCALE)
  short8 qa0, qa1;
  {
    const u16* qp = Qb + hbase + (size_t)(q0w + cc) * C + hi * 8;
    qa0 = *(const short8*)qp;
    qa1 = *(const short8*)(qp + 32);
  }

  f32x4 o[4];   // o[dc]: O rows q = hi4+r, cols d = dc*16+cc
#pragma unroll
  for (int dc = 0; dc < 4; ++dc) o[dc] = f32x4{0.f, 0.f, 0.f, 0.f};
  float mrow = -1e30f, lsum = 0.f;   // per q = cc

  // staging maps (512 threads): 16B K + 16B V per thread
  const int krow = tid >> 3, kcol = (tid & 7) * 8;            // K: u16 units
  const int vd0 = (tid & 31) * 2, vkey0 = (tid >> 5) * 4;     // V: 16 groups x 4 keys
  const u16* kgp = Kb + hbase + (size_t)krow * C + kcol;
  const u16* vgp = Vb + hbase + (size_t)vkey0 * C + vd0;

  short8 kr0;
  u32 vr_[4];

  auto LOADT = [&](int kt) {
    const size_t off = (size_t)(kt * 64) * C;
    kr0 = *(const short8*)(kgp + off);
#pragma unroll
    for (int j = 0; j < 4; ++j)
      vr_[j] = *(const u32*)(vgp + off + (size_t)j * C);
  };

  char* KsB = (char*)Ks;
  char* VtB = (char*)Vt;

  auto WRITET = [&]() {
    const int kb = krow * 128 + kcol * 2;
    const int ksw = (krow & 7) << 4;
    *(short8*)(KsB + (kb ^ ksw)) = kr0;
    u32 lo0 = (vr_[0] & 0xFFFFu) | (vr_[1] << 16);
    u32 lo1 = (vr_[2] & 0xFFFFu) | (vr_[3] << 16);
    u32 hh0 = (vr_[0] >> 16) | (vr_[1] & 0xFFFF0000u);
    u32 hh1 = (vr_[2] >> 16) | (vr_[3] & 0xFFFF0000u);
    const int d1 = vd0 + 1;
    u32x2 vlo = {lo0, lo1};
    u32x2 vhi = {hh0, hh1};
    *(u32x2*)(VtB + ((vd0 * 128 + vkey0 * 2) ^ ((vd0 & 7) << 4))) = vlo;
    *(u32x2*)(VtB + ((d1 * 128 + vkey0 * 2) ^ ((d1 & 7) << 4))) = vhi;
  };

  const int ksw2 = (cc & 7) << 4;

  // prologue: stage tile 0, prefetch tile 1 (qtB >= 16)
  LOADT(0);
  WRITET();
  LOADT(1);
  __syncthreads();

  for (int kt = 0; kt <= qtB; ++kt) {
    const bool act = (kt <= qtW);
    if (act) {
      // S^T = K Q^T (kf read JIT)
      f32x4 s[4];
#pragma unroll
      for (int nt = 0; nt < 4; ++nt) {
        const int kb = (nt * 16 + cc) * 128 + hi * 16;
        short8 kf0 = *(const short8*)(KsB + (kb ^ ksw2));
        short8 kf1 = *(const short8*)(KsB + ((kb + 64) ^ ksw2));
        f32x4 z = f32x4{0.f, 0.f, 0.f, 0.f};
        z = MFMA32(kf0, qa0, z);
        z = MFMA32(kf1, qa1, z);
        s[nt] = z;
      }

      if (kt == qtW) {             // diagonal tile: mask local key > local q
        const int qloc = wl * 16 + cc;
#pragma unroll
        for (int nt = 0; nt < 4; ++nt)
#pragma unroll
          for (int r = 0; r < 4; ++r)
            if (nt * 16 + hi4 + r > qloc) s[nt][r] = -1e30f;
      }

      // softmax (exp2 domain, defer-max); P packed into regs = PV A-frags
      float tm = s[0][0];
#pragma unroll
      for (int nt = 0; nt < 4; ++nt)
#pragma unroll
        for (int r = 0; r < 4; ++r) tm = fmaxf(tm, s[nt][r]);
      tm = fmaxf(tm, __shfl_xor(tm, 16));
      tm = fmaxf(tm, __shfl_xor(tm, 32));
      const bool need = tm > mrow + 8.0f;
      float corr = 1.0f;
      if (need) { corr = exp2f(mrow - tm); mrow = tm; }

      short4v pa[4];
      float psum = 0.f;
#pragma unroll
      for (int nt = 0; nt < 4; ++nt) {
        float e0 = exp2f(s[nt][0] - mrow);
        float e1 = exp2f(s[nt][1] - mrow);
        float e2 = exp2f(s[nt][2] - mrow);
        float e3 = exp2f(s[nt][3] - mrow);
        psum += (e0 + e1) + (e2 + e3);
        union { u32 u[2]; short4v v; } pu;
        pu.u[0] = pk_bf16(e0, e1);
        pu.u[1] = pk_bf16(e2, e3);
        pa[nt] = pu.v;
      }
      psum += __shfl_xor(psum, 16);
      psum += __shfl_xor(psum, 32);
      lsum = lsum * corr + psum;

      if (__any(need)) {           // o rows live at q = hi4+r -> shuffle corr
        f32x4 cv;
        cv[0] = __shfl(corr, hi4 + 0);
        cv[1] = __shfl(corr, hi4 + 1);
        cv[2] = __shfl(corr, hi4 + 2);
        cv[3] = __shfl(corr, hi4 + 3);
#pragma unroll
        for (int dc = 0; dc < 4; ++dc) o[dc] *= cv;
      }

      // O += P V via 16x16x16: A = pa[nt] (reg), B = V^T fragment (JIT b64 read)
#pragma unroll
      for (int nt = 0; nt < 4; ++nt)
#pragma unroll
        for (int dc = 0; dc < 4; ++dc) {
          short4v vb = *(const short4v*)(VtB + (((dc * 16 + cc) * 128 + nt * 32 + hi * 8) ^ ksw2));
          o[dc] = mfma16(pa[nt], vb, o[dc]);
        }
    }

    if (kt < qtB) {
      __syncthreads();             // all waves done reading Ks/Vt
      WRITET();                    // stage tile kt+1 (regs from last LOADT)
      if (kt + 1 < qtB) LOADT(kt + 2);   // prefetch tile kt+2
      __syncthreads();             // staged tile visible
    }
  }

  // epilogue: lsum lives at q=cc -> shuffle to q=hi4+r rows
  f32x4 iv;
  iv[0] = 1.0f / __shfl(lsum, hi4 + 0);
  iv[1] = 1.0f / __shfl(lsum, hi4 + 1);
  iv[2] = 1.0f / __shfl(lsum, hi4 + 2);
  iv[3] = 1.0f / __shfl(lsum, hi4 + 3);
#pragma unroll
  for (int dc = 0; dc < 4; ++dc)
#pragma unroll
    for (int r = 0; r < 4; ++r)
      Yb[hbase + (size_t)(q0w + hi4 + r) * C + dc * 16 + cc] = f2bf(o[dc][r] * iv[r]);
}

// ---------------- proj GEMM: BN=64, BK=64, fp32 out, swizzled LDS, XCD remap ----------------
__global__ __launch_bounds__(256, 2) void gemm_proj(
    const u16* __restrict__ A, const u16* __restrict__ W,
    const float* __restrict__ bias, float* __restrict__ Out) {
  const int K = 1024, N = 1024;
  __shared__ __attribute__((aligned(16))) u16 As[128 * 64];
  __shared__ __attribute__((aligned(16))) u16 Bs[64 * 64];
  const int tid = threadIdx.x;
  const int lane = tid & 63;
  const int hi = lane >> 4, cc = lane & 15;
  const int w = tid >> 6, wm = w >> 1, wn = w & 1;

  const int lin = blockIdx.x + 16 * blockIdx.y;   // gridDim (16, 32)
  const int colt = (lin & 7) * 2 + ((lin >> 3) & 1);
  const int row0 = (lin >> 4) * 128, col0 = colt * 64;

  const int lr = tid >> 3;
  const int lkb = (((tid & 7) ^ (lr & 7)) * 8);
  const u16* Ag = A + (size_t)(row0 + lr) * K + lkb;
  const u16* Wg = W + (size_t)(col0 + lr) * K + lkb;

  f32x4 acc[4][2];
#pragma unroll
  for (int m = 0; m < 4; ++m)
#pragma unroll
    for (int n = 0; n < 2; ++n) acc[m][n] = f32x4{0.f, 0.f, 0.f, 0.f};

  for (int k0 = 0; k0 < K; k0 += 64) {
    __syncthreads();
#pragma unroll
    for (int j = 0; j < 4; ++j)
      gl_lds16(Ag + (size_t)j * 32 * K + k0, As + j * 2048 + tid * 8);
#pragma unroll
    for (int j = 0; j < 2; ++j)
      gl_lds16(Wg + (size_t)j * 32 * K + k0, Bs + j * 2048 + tid * 8);
    __syncthreads();
    short8 a[2][4], b[2][2];
#pragma unroll
    for (int kk = 0; kk < 2; ++kk) {
#pragma unroll
      for (int m = 0; m < 4; ++m)
        a[kk][m] = *(const short8*)(As + (wm * 64 + m * 16 + cc) * 64 +
                                    (((kk * 4 + hi) ^ (cc & 7)) * 8));
#pragma unroll
      for (int n = 0; n < 2; ++n)
        b[kk][n] = *(const short8*)(Bs + (wn * 32 + n * 16 + cc) * 64 +
                                    (((kk * 4 + hi) ^ (cc & 7)) * 8));
    }
#pragma unroll
    for (int kk = 0; kk < 2; ++kk)
#pragma unroll
      for (int m = 0; m < 4; ++m)
#pragma unroll
        for (int n = 0; n < 2; ++n)
          acc[m][n] = MFMA32(a[kk][m], b[kk][n], acc[m][n]);
  }

#pragma unroll
  for (int n = 0; n < 2; ++n) {
    const int col = col0 + wn * 32 + n * 16 + cc;
    const float bb = bias[col];
#pragma unroll
    for (int m = 0; m < 4; ++m) {
      const int rw = row0 + wm * 64 + m * 16 + hi * 4;
#pragma unroll
      for (int r = 0; r < 4; ++r)
        Out[(size_t)(rw + r) * N + col] = acc[m][n][r] + bb;
    }
  }
}

extern "C" void kernel_launch(void* const* d_in, const int* in_sizes, int n_in,
                              void* d_out, int out_size, void* d_ws, size_t ws_size,
                              hipStream_t stream) {
  const float* x  = (const float*)d_in[0];
  const float* Wq = (const float*)d_in[1];
  const float* bq = (const float*)d_in[2];
  const float* Wk = (const float*)d_in[3];
  const float* bk = (const float*)d_in[4];
  const float* Wv = (const float*)d_in[5];
  const float* bv = (const float*)d_in[6];
  const float* Wp = (const float*)d_in[7];
  const float* bp = (const float*)d_in[8];
  float* out = (float*)d_out;

  const int B = 2, T = 2048, C = 1024;
  const int M = B * T;
  const size_t MC = (size_t)M * C;
  const size_t CC = (size_t)C * C;

  char* p = (char*)d_ws;
  u16* xb  = (u16*)p;  p += MC * 2;    // reused as Y after QKV GEMM
  u16* Wqb = (u16*)p;  p += CC * 2;
  u16* Wkb = (u16*)p;  p += CC * 2;
  u16* Wvb = (u16*)p;  p += CC * 2;
  u16* Wpb = (u16*)p;  p += CC * 2;
  u16* Qbb = (u16*)p;  p += MC * 2;
  u16* Kbb = (u16*)p;  p += MC * 2;
  u16* Vbb = (u16*)p;  p += MC * 2;
  float* cosT = (float*)p; p += (size_t)T * 32 * 4;
  float* sinT = (float*)p; p += (size_t)T * 32 * 4;

  const int n4x = (int)(MC / 4);
  const int n4tot = n4x + 4 * (int)(CC / 4);
  const int ntot = n4tot + T * 32;     // + RoPE table items
  cvt_all<<<(ntot + 255) / 256, 256, 0, stream>>>(x, Wq, Wk, Wv, Wp,
                                                  xb, Wqb, Wkb, Wvb, Wpb,
                                                  cosT, sinT, n4x, n4tot);

  dim3 gq(24, M / 128);
  gemm_qkv<<<gq, 256, 0, stream>>>(xb, Wqb, Wkb, Wvb, bq, bk, bv, cosT, sinT, Qbb, Kbb, Vbb);

  dim3 fg(16, B * 16);
  flash_mfma<<<fg, 512, 0, stream>>>(Qbb, Kbb, Vbb, xb);   // Y -> xb (reuse)

  dim3 gp(C / 64, M / 128);
  gemm_proj<<<gp, 256, 0, stream>>>(xb, Wpb, bp, out);
}

// Round 19
// 113.314 us; speedup vs baseline: 1.0138x; 1.0138x over previous
//
#include <hip/hip_runtime.h>
#include <math.h>

typedef unsigned short u16;
typedef unsigned int u32;
typedef unsigned long long u64;
typedef __attribute__((ext_vector_type(8))) short short8;
typedef __attribute__((ext_vector_type(4))) short short4v;
typedef __attribute__((ext_vector_type(4))) float f32x4;
typedef __attribute__((ext_vector_type(4))) u16 u16x4;
typedef __attribute__((ext_vector_type(2))) u32 u32x2;
typedef __attribute__((ext_vector_type(4))) u32 u32x4;

#define AS1 __attribute__((address_space(1)))
#define AS3 __attribute__((address_space(3)))

// 0.125 * log2(e): QK^T scores scaled so softmax = exp2
#define QSCALE 0.18033688011112042f

__device__ __forceinline__ u16 f2bf(float f) {
  union { float f; u32 i; } u; u.f = f;
  u32 r = u.i + 0x7FFFu + ((u.i >> 16) & 1u);
  return (u16)(r >> 16);
}

__device__ __forceinline__ u32 pk_bf16(float a, float b) {
  u32 r;
  asm volatile("v_cvt_pk_bf16_f32 %0, %1, %2" : "=v"(r) : "v"(a), "v"(b));
  return r;
}

__device__ __forceinline__ void gl_lds16(const void* g, void* l) {
  __builtin_amdgcn_global_load_lds((const AS1 u32*)g, (AS3 u32*)l, 16, 0, 0);
}

#define MFMA32(a, b, c) __builtin_amdgcn_mfma_f32_16x16x32_bf16(a, b, c, 0, 0, 0)

__device__ __forceinline__ f32x4 mfma16(short4v a, short4v b, f32x4 c) {
#if __has_builtin(__builtin_amdgcn_mfma_f32_16x16x16_bf16)
  return __builtin_amdgcn_mfma_f32_16x16x16_bf16(a, b, c, 0, 0, 0);
#elif __has_builtin(__builtin_amdgcn_mfma_f32_16x16x16bf16_1k)
  return __builtin_amdgcn_mfma_f32_16x16x16bf16_1k(a, b, c, 0, 0, 0);
#else
  f32x4 d = c;
  asm("v_mfma_f32_16x16x16_bf16 %0, %1, %2, %0" : "+v"(d) : "v"(a), "v"(b));
  return d;
#endif
}

// ---------------- fused convert (x + 4 weights, 32B/thread) + RoPE table ----------------
__global__ void cvt_all(const float* __restrict__ x,
                        const float* __restrict__ Wq, const float* __restrict__ Wk,
                        const float* __restrict__ Wv, const float* __restrict__ Wp,
                        u16* __restrict__ xb,
                        u16* __restrict__ Wqb, u16* __restrict__ Wkb,
                        u16* __restrict__ Wvb, u16* __restrict__ Wpb,
                        float* __restrict__ cosT, float* __restrict__ sinT,
                        int n4x, int nhalf) {
  int i = blockIdx.x * 256 + threadIdx.x;
  if (i >= nhalf) {                    // RoPE table tail: 65536 items
    int k = i - nhalf;
    int t = k >> 5, j = k & 31;
    float inv = powf(10000.0f, -(float)j / 32.0f);
    float ang = (float)t * inv;
    cosT[k] = cosf(ang);
    sinT[k] = sinf(ang);
    return;
  }
  const int i2 = i * 2;                // array boundaries are even: pair never straddles
  const float* src; u16* dst; int off;
  if (i2 < n4x) { src = x; dst = xb; off = i2; }
  else {
    int wi = i2 - n4x;
    int sel = wi >> 18;                // CC/4 = 2^18
    off = wi & ((1 << 18) - 1);
    src = sel == 0 ? Wq : sel == 1 ? Wk : sel == 2 ? Wv : Wp;
    dst = sel == 0 ? Wqb : sel == 1 ? Wkb : sel == 2 ? Wvb : Wpb;
  }
  float4 v0 = ((const float4*)src)[off];
  float4 v1 = ((const float4*)src)[off + 1];
  u16x4 o0 = { f2bf(v0.x), f2bf(v0.y), f2bf(v0.z), f2bf(v0.w) };
  u16x4 o1 = { f2bf(v1.x), f2bf(v1.y), f2bf(v1.z), f2bf(v1.w) };
  ((u16x4*)dst)[off] = o0;
  ((u16x4*)dst)[off + 1] = o1;
}

// ---------------- fused QKV GEMM (bf16 MFMA), BK=64, RoPE epilogue ----------------
__global__ __launch_bounds__(256, 3) void gemm_qkv(
    const u16* __restrict__ xb,
    const u16* __restrict__ Wqb, const u16* __restrict__ Wkb, const u16* __restrict__ Wvb,
    const float* __restrict__ bq, const float* __restrict__ bk, const float* __restrict__ bv,
    const float* __restrict__ cosT, const float* __restrict__ sinT,
    u16* __restrict__ Qb, u16* __restrict__ Kb, u16* __restrict__ Vb) {
  const int K = 1024, N = 1024;
  __shared__ __attribute__((aligned(16))) u16 As[128 * 64];
  __shared__ __attribute__((aligned(16))) u16 Bs[128 * 64];
  const int tid = threadIdx.x;
  const int lane = tid & 63;
  const int hi = lane >> 4, cc = lane & 15;
  const int w = tid >> 6, wm = w >> 1, wn = w & 1;

  const int lin = blockIdx.x + 24 * blockIdx.y;   // gridDim (24, 32)
  const int a_ = lin & 7;
  const int m_ = lin >> 3;
  const int c_ = a_ * 3 + (m_ % 3);               // 0..23: sel*8 + colt
  const int sel = c_ >> 3;
  const int row0 = (m_ / 3) * 128, col0 = (c_ & 7) * 128;

  const u16* W = sel == 0 ? Wqb : sel == 1 ? Wkb : Wvb;
  const float* bias = sel == 0 ? bq : sel == 1 ? bk : bv;
  u16* Out = sel == 0 ? Qb : sel == 1 ? Kb : Vb;

  const int lr = tid >> 3;                                   // 0..31
  const int lkb = (((tid & 7) ^ (lr & 7)) * 8);              // pre-swizzled src col
  const u16* Ag = xb + (size_t)(row0 + lr) * K + lkb;
  const u16* Wg = W + (size_t)(col0 + lr) * K + lkb;

  f32x4 acc[4][4];
#pragma unroll
  for (int m = 0; m < 4; ++m)
#pragma unroll
    for (int n = 0; n < 4; ++n) acc[m][n] = f32x4{0.f, 0.f, 0.f, 0.f};

  for (int k0 = 0; k0 < K; k0 += 64) {
    __syncthreads();
#pragma unroll
    for (int j = 0; j < 4; ++j) {
      gl_lds16(Ag + (size_t)j * 32 * K + k0, As + j * 2048 + tid * 8);
      gl_lds16(Wg + (size_t)j * 32 * K + k0, Bs + j * 2048 + tid * 8);
    }
    __syncthreads();
    short8 a[2][4], b[2][4];
#pragma unroll
    for (int kk = 0; kk < 2; ++kk) {
#pragma unroll
      for (int m = 0; m < 4; ++m)
        a[kk][m] = *(const short8*)(As + (wm * 64 + m * 16 + cc) * 64 +
                                    (((kk * 4 + hi) ^ (cc & 7)) * 8));
#pragma unroll
      for (int n = 0; n < 4; ++n)
        b[kk][n] = *(const short8*)(Bs + (wn * 64 + n * 16 + cc) * 64 +
                                    (((kk * 4 + hi) ^ (cc & 7)) * 8));
    }
#pragma unroll
    for (int kk = 0; kk < 2; ++kk)
#pragma unroll
      for (int m = 0; m < 4; ++m)
#pragma unroll
        for (int n = 0; n < 4; ++n)
          acc[m][n] = MFMA32(a[kk][m], b[kk][n], acc[m][n]);
  }

  if (sel < 2) {
    const float qs = (sel == 0) ? QSCALE : 1.0f;
#pragma unroll
    for (int n = 0; n < 4; ++n) {
      const int col = col0 + wn * 64 + n * 16 + cc;
      const int j = (col & 63) >> 1;
      const float bb = bias[col];
#pragma unroll
      for (int m = 0; m < 4; ++m) {
        const int rw = row0 + wm * 64 + m * 16 + hi * 4;
#pragma unroll
        for (int r = 0; r < 4; ++r) {
          const int row = rw + r;
          const int t = row & 2047;
          float v = acc[m][n][r] + bb;
          float pv = __shfl_xor(v, 1);
          float c = cosT[t * 32 + j], s = sinT[t * 32 + j];
          float oo = (cc & 1) ? (s * pv + c * v) : (c * v - s * pv);
          Out[(size_t)row * N + col] = f2bf(oo * qs);
        }
      }
    }
  } else {
#pragma unroll
    for (int n = 0; n < 4; ++n) {
      const int col = col0 + wn * 64 + n * 16 + cc;
      const float bb = bias[col];
#pragma unroll
      for (int m = 0; m < 4; ++m) {
        const int rw = row0 + wm * 64 + m * 16 + hi * 4;
#pragma unroll
        for (int r = 0; r < 4; ++r)
          Out[(size_t)(rw + r) * N + col] = f2bf(acc[m][n][r] + bb);
      }
    }
  }
}

// ---------------- MFMA causal flash attention: 512-thread blocks, reg-P PV (x16) ----------------
// Vt uses a key->slot permutation (slot = hi(key)*16 + nt(key)*4 + j) so each
// PV B-fragment pair is one conflict-free ds_read_b128 (was 16 conflicted b64).
__global__ __launch_bounds__(512, 3) void flash_mfma(
    const u16* __restrict__ Qb, const u16* __restrict__ Kb,
    const u16* __restrict__ Vb, u16* __restrict__ Yb) {
  const int T = 2048, C = 1024;
  __shared__ __attribute__((aligned(16))) u16 Ks[64 * 64];      // swizzled [key][d]
  __shared__ __attribute__((aligned(16))) u16 Vt[64 * 64];      // swizzled [d][slot]

  const int tid = threadIdx.x;
  const int lane = tid & 63;
  const int hi = lane >> 4, cc = lane & 15;
  const int hi4 = hi * 4;
  const int w = tid >> 6;                       // 0..7
  const int wl = w & 3;                         // slice within chunk
  const int isB = w >> 2;                       // 0 = chunk A, 1 = chunk B

  const int lin = blockIdx.x + 16 * blockIdx.y; // gridDim (16, 32)
  const int bh  = (lin & 7) * 4 + ((lin >> 3) & 3);
  const int qtA = lin >> 5;                     // 0..15
  const int qtB = 31 - qtA;                     // 16..31
  const int qtW = isB ? qtB : qtA;              // this wave's chunk
  const size_t hbase = (size_t)(bh >> 4) * T * C + (size_t)(bh & 15) * 64;
  const int q0w = qtW * 64 + wl * 16;

  // Q fragment (B-operand of swapped QK^T; Q pre-scaled by QSCALE)
  short8 qa0, qa1;
  {
    const u16* qp = Qb + hbase + (size_t)(q0w + cc) * C + hi * 8;
    qa0 = *(const short8*)qp;
    qa1 = *(const short8*)(qp + 32);
  }

  f32x4 o[4];   // o[dc]: O rows q = hi4+r, cols d = dc*16+cc
#pragma unroll
  for (int dc = 0; dc < 4; ++dc) o[dc] = f32x4{0.f, 0.f, 0.f, 0.f};
  float mrow = -1e30f, lsum = 0.f;   // per q = cc

  // staging maps (512 threads): 16B K + 16B V per thread
  const int krow = tid >> 3, kcol = (tid & 7) * 8;            // K: u16 units
  const int vd0 = (tid & 31) * 2, vkey0 = (tid >> 5) * 4;     // V: 16 groups x 4 keys
  const int g = tid >> 5;                                     // key group 0..15
  const int sb = (g & 3) * 16 + (g >> 2) * 4;                 // slot base (permuted)
  const u16* kgp = Kb + hbase + (size_t)krow * C + kcol;
  const u16* vgp = Vb + hbase + (size_t)vkey0 * C + vd0;

  short8 kr0;
  u32 vr_[4];

  auto LOADT = [&](int kt) {
    const size_t off = (size_t)(kt * 64) * C;
    kr0 = *(const short8*)(kgp + off);
#pragma unroll
    for (int j = 0; j < 4; ++j)
      vr_[j] = *(const u32*)(vgp + off + (size_t)j * C);
  };

  char* KsB = (char*)Ks;
  char* VtB = (char*)Vt;

  auto WRITET = [&]() {
    const int kb = krow * 128 + kcol * 2;
    const int ksw = (krow & 7) << 4;
    *(short8*)(KsB + (kb ^ ksw)) = kr0;
    u32 lo0 = (vr_[0] & 0xFFFFu) | (vr_[1] << 16);
    u32 lo1 = (vr_[2] & 0xFFFFu) | (vr_[3] << 16);
    u32 hh0 = (vr_[0] >> 16) | (vr_[1] & 0xFFFF0000u);
    u32 hh1 = (vr_[2] >> 16) | (vr_[3] & 0xFFFF0000u);
    const int d1 = vd0 + 1;
    u32x2 vlo = {lo0, lo1};
    u32x2 vhi = {hh0, hh1};
    *(u32x2*)(VtB + ((vd0 * 128 + sb * 2) ^ ((vd0 & 7) << 4))) = vlo;
    *(u32x2*)(VtB + ((d1 * 128 + sb * 2) ^ ((d1 & 7) << 4))) = vhi;
  };

  const int ksw2 = (cc & 7) << 4;

  // prologue: stage tile 0, prefetch tile 1 (qtB >= 16)
  LOADT(0);
  WRITET();
  LOADT(1);
  __syncthreads();

  for (int kt = 0; kt <= qtB; ++kt) {
    const bool act = (kt <= qtW);
    if (act) {
      // S^T = K Q^T (kf read JIT)
      f32x4 s[4];
#pragma unroll
      for (int nt = 0; nt < 4; ++nt) {
        const int kb = (nt * 16 + cc) * 128 + hi * 16;
        short8 kf0 = *(const short8*)(KsB + (kb ^ ksw2));
        short8 kf1 = *(const short8*)(KsB + ((kb + 64) ^ ksw2));
        f32x4 z = f32x4{0.f, 0.f, 0.f, 0.f};
        z = MFMA32(kf0, qa0, z);
        z = MFMA32(kf1, qa1, z);
        s[nt] = z;
      }

      if (kt == qtW) {             // diagonal tile: mask local key > local q
        const int qloc = wl * 16 + cc;
#pragma unroll
        for (int nt = 0; nt < 4; ++nt)
#pragma unroll
          for (int r = 0; r < 4; ++r)
            if (nt * 16 + hi4 + r > qloc) s[nt][r] = -1e30f;
      }

      // softmax (exp2 domain, defer-max); P packed into regs = PV A-frags
      float tm = s[0][0];
#pragma unroll
      for (int nt = 0; nt < 4; ++nt)
#pragma unroll
        for (int r = 0; r < 4; ++r) tm = fmaxf(tm, s[nt][r]);
      tm = fmaxf(tm, __shfl_xor(tm, 16));
      tm = fmaxf(tm, __shfl_xor(tm, 32));
      const bool need = tm > mrow + 8.0f;
      float corr = 1.0f;
      if (need) { corr = exp2f(mrow - tm); mrow = tm; }

      short4v pa[4];
      float psum = 0.f;
#pragma unroll
      for (int nt = 0; nt < 4; ++nt) {
        float e0 = exp2f(s[nt][0] - mrow);
        float e1 = exp2f(s[nt][1] - mrow);
        float e2 = exp2f(s[nt][2] - mrow);
        float e3 = exp2f(s[nt][3] - mrow);
        psum += (e0 + e1) + (e2 + e3);
        union { u32 u[2]; short4v v; } pu;
        pu.u[0] = pk_bf16(e0, e1);
        pu.u[1] = pk_bf16(e2, e3);
        pa[nt] = pu.v;
      }
      psum += __shfl_xor(psum, 16);
      psum += __shfl_xor(psum, 32);
      lsum = lsum * corr + psum;

      if (__any(need)) {           // o rows live at q = hi4+r -> shuffle corr
        f32x4 cv;
        cv[0] = __shfl(corr, hi4 + 0);
        cv[1] = __shfl(corr, hi4 + 1);
        cv[2] = __shfl(corr, hi4 + 2);
        cv[3] = __shfl(corr, hi4 + 3);
#pragma unroll
        for (int dc = 0; dc < 4; ++dc) o[dc] *= cv;
      }

      // O += P V via 16x16x16: one b128 feeds two mfma16 (slot permutation)
#pragma unroll
      for (int np = 0; np < 2; ++np)
#pragma unroll
        for (int dc = 0; dc < 4; ++dc) {
          short8 vb2 = *(const short8*)(VtB + (((dc * 16 + cc) * 128 + hi * 32 + np * 16) ^ ksw2));
          short4v vlo = __builtin_shufflevector(vb2, vb2, 0, 1, 2, 3);
          short4v vhi = __builtin_shufflevector(vb2, vb2, 4, 5, 6, 7);
          o[dc] = mfma16(pa[2 * np], vlo, o[dc]);
          o[dc] = mfma16(pa[2 * np + 1], vhi, o[dc]);
        }
    }

    if (kt < qtB) {
      __syncthreads();             // all waves done reading Ks/Vt
      WRITET();                    // stage tile kt+1 (regs from last LOADT)
      if (kt + 1 < qtB) LOADT(kt + 2);   // prefetch tile kt+2
      __syncthreads();             // staged tile visible
    }
  }

  // epilogue: lsum lives at q=cc -> shuffle to q=hi4+r rows
  f32x4 iv;
  iv[0] = 1.0f / __shfl(lsum, hi4 + 0);
  iv[1] = 1.0f / __shfl(lsum, hi4 + 1);
  iv[2] = 1.0f / __shfl(lsum, hi4 + 2);
  iv[3] = 1.0f / __shfl(lsum, hi4 + 3);
#pragma unroll
  for (int dc = 0; dc < 4; ++dc)
#pragma unroll
    for (int r = 0; r < 4; ++r)
      Yb[hbase + (size_t)(q0w + hi4 + r) * C + dc * 16 + cc] = f2bf(o[dc][r] * iv[r]);
}

// ---------------- proj GEMM: BN=64, BK=64, fp32 out, swizzled LDS, XCD remap ----------------
__global__ __launch_bounds__(256, 2) void gemm_proj(
    const u16* __restrict__ A, const u16* __restrict__ W,
    const float* __restrict__ bias, float* __restrict__ Out) {
  const int K = 1024, N = 1024;
  __shared__ __attribute__((aligned(16))) u16 As[128 * 64];
  __shared__ __attribute__((aligned(16))) u16 Bs[64 * 64];
  const int tid = threadIdx.x;
  const int lane = tid & 63;
  const int hi = lane >> 4, cc = lane & 15;
  const int w = tid >> 6, wm = w >> 1, wn = w & 1;

  const int lin = blockIdx.x + 16 * blockIdx.y;   // gridDim (16, 32)
  const int colt = (lin & 7) * 2 + ((lin >> 3) & 1);
  const int row0 = (lin >> 4) * 128, col0 = colt * 64;

  const int lr = tid >> 3;
  const int lkb = (((tid & 7) ^ (lr & 7)) * 8);
  const u16* Ag = A + (size_t)(row0 + lr) * K + lkb;
  const u16* Wg = W + (size_t)(col0 + lr) * K + lkb;

  f32x4 acc[4][2];
#pragma unroll
  for (int m = 0; m < 4; ++m)
#pragma unroll
    for (int n = 0; n < 2; ++n) acc[m][n] = f32x4{0.f, 0.f, 0.f, 0.f};

  for (int k0 = 0; k0 < K; k0 += 64) {
    __syncthreads();
#pragma unroll
    for (int j = 0; j < 4; ++j)
      gl_lds16(Ag + (size_t)j * 32 * K + k0, As + j * 2048 + tid * 8);
#pragma unroll
    for (int j = 0; j < 2; ++j)
      gl_lds16(Wg + (size_t)j * 32 * K + k0, Bs + j * 2048 + tid * 8);
    __syncthreads();
    short8 a[2][4], b[2][2];
#pragma unroll
    for (int kk = 0; kk < 2; ++kk) {
#pragma unroll
      for (int m = 0; m < 4; ++m)
        a[kk][m] = *(const short8*)(As + (wm * 64 + m * 16 + cc) * 64 +
                                    (((kk * 4 + hi) ^ (cc & 7)) * 8));
#pragma unroll
      for (int n = 0; n < 2; ++n)
        b[kk][n] = *(const short8*)(Bs + (wn * 32 + n * 16 + cc) * 64 +
                                    (((kk * 4 + hi) ^ (cc & 7)) * 8));
    }
#pragma unroll
    for (int kk = 0; kk < 2; ++kk)
#pragma unroll
      for (int m = 0; m < 4; ++m)
#pragma unroll
        for (int n = 0; n < 2; ++n)
          acc[m][n] = MFMA32(a[kk][m], b[kk][n], acc[m][n]);
  }

#pragma unroll
  for (int n = 0; n < 2; ++n) {
    const int col = col0 + wn * 32 + n * 16 + cc;
    const float bb = bias[col];
#pragma unroll
    for (int m = 0; m < 4; ++m) {
      const int rw = row0 + wm * 64 + m * 16 + hi * 4;
#pragma unroll
      for (int r = 0; r < 4; ++r)
        Out[(size_t)(rw + r) * N + col] = acc[m][n][r] + bb;
    }
  }
}

extern "C" void kernel_launch(void* const* d_in, const int* in_sizes, int n_in,
                              void* d_out, int out_size, void* d_ws, size_t ws_size,
                              hipStream_t stream) {
  const float* x  = (const float*)d_in[0];
  const float* Wq = (const float*)d_in[1];
  const float* bq = (const float*)d_in[2];
  const float* Wk = (const float*)d_in[3];
  const float* bk = (const float*)d_in[4];
  const float* Wv = (const float*)d_in[5];
  const float* bv = (const float*)d_in[6];
  const float* Wp = (const float*)d_in[7];
  const float* bp = (const float*)d_in[8];
  float* out = (float*)d_out;

  const int B = 2, T = 2048, C = 1024;
  const int M = B * T;
  const size_t MC = (size_t)M * C;
  const size_t CC = (size_t)C * C;

  char* p = (char*)d_ws;
  u16* xb  = (u16*)p;  p += MC * 2;    // reused as Y after QKV GEMM
  u16* Wqb = (u16*)p;  p += CC * 2;
  u16* Wkb = (u16*)p;  p += CC * 2;
  u16* Wvb = (u16*)p;  p += CC * 2;
  u16* Wpb = (u16*)p;  p += CC * 2;
  u16* Qbb = (u16*)p;  p += MC * 2;
  u16* Kbb = (u16*)p;  p += MC * 2;
  u16* Vbb = (u16*)p;  p += MC * 2;
  float* cosT = (float*)p; p += (size_t)T * 32 * 4;
  float* sinT = (float*)p; p += (size_t)T * 32 * 4;

  const int n4x = (int)(MC / 4);
  const int n4tot = n4x + 4 * (int)(CC / 4);
  const int nhalf = n4tot / 2;
  const int ntot = nhalf + T * 32;
  cvt_all<<<(ntot + 255) / 256, 256, 0, stream>>>(x, Wq, Wk, Wv, Wp,
                                                  xb, Wqb, Wkb, Wvb, Wpb,
                                                  cosT, sinT, n4x, nhalf);

  dim3 gq(24, M / 128);
  gemm_qkv<<<gq, 256, 0, stream>>>(xb, Wqb, Wkb, Wvb, bq, bk, bv, cosT, sinT, Qbb, Kbb, Vbb);

  dim3 fg(16, B * 16);
  flash_mfma<<<fg, 512, 0, stream>>>(Qbb, Kbb, Vbb, xb);   // Y -> xb (reuse)

  dim3 gp(C / 64, M / 128);
  gemm_proj<<<gp, 256, 0, stream>>>(xb, Wpb, bp, out);
}